// Round 15
// baseline (7016.696 us; speedup 1.0000x reference)
//
#include <hip/hip_runtime.h>
#include <hip/hip_bf16.h>
#include <cstdint>

#define T_DIM 4096
#define D_DIM 4096
#define I_DIM 12288
#define GRP   128

typedef __attribute__((ext_vector_type(8))) short bf16x8;
typedef __attribute__((ext_vector_type(4))) float f32x4;
typedef __attribute__((ext_vector_type(4))) int   int32x4;

typedef __attribute__((address_space(3))) void lds_void;
typedef const __attribute__((address_space(1))) void gmem_void;

static __device__ __forceinline__ unsigned short f2bf(float f) {
    unsigned int u = __float_as_uint(f);
    u += 0x7FFFu + ((u >> 16) & 1u);
    return (unsigned short)(u >> 16);
}
static __device__ __forceinline__ float bf2f(unsigned short b) {
    return __uint_as_float(((unsigned int)b) << 16);
}

// ---------- Hadamard + int8 quant (per-128-group scale), one wave per group --------
__global__ void had_f32_to_i8(const float* __restrict__ in, signed char* __restrict__ outq,
                              float* __restrict__ outs, int ngroups) {
    int gid = blockIdx.x * (blockDim.x >> 6) + (threadIdx.x >> 6);
    if (gid >= ngroups) return;
    int lane = threadIdx.x & 63;
    const float2 v2 = *reinterpret_cast<const float2*>(in + (size_t)gid * 128 + lane * 2);
    float v0 = v2.x, v1 = v2.y;
    { float t0 = v0 + v1, t1 = v0 - v1; v0 = t0; v1 = t1; }
#pragma unroll
    for (int m = 1; m <= 32; m <<= 1) {
        float b0 = __shfl_xor(v0, m);
        float b1 = __shfl_xor(v1, m);
        if (lane & m) { v0 = b0 - v0; v1 = b1 - v1; }
        else          { v0 = v0 + b0; v1 = v1 + b1; }
    }
    const float s = 0.08838834764831843f;  // 1/sqrt(128)
    v0 *= s; v1 *= s;
    float am = fmaxf(fabsf(v0), fabsf(v1));
#pragma unroll
    for (int m = 1; m <= 32; m <<= 1) am = fmaxf(am, __shfl_xor(am, m));
    float inv = (am > 0.f) ? 127.0f / am : 0.f;
    int q0 = (int)rintf(v0 * inv);
    int q1 = (int)rintf(v1 * inv);
    unsigned short pk = (unsigned short)((q0 & 0xff) | ((q1 & 0xff) << 8));
    *reinterpret_cast<unsigned short*>(outq + (size_t)gid * 128 + lane * 2) = pk;
    if (lane == 0) outs[gid] = (am > 0.f) ? am / 127.0f : 1.0f;
}

__global__ void had_bf16_to_i8(const unsigned short* __restrict__ in, signed char* __restrict__ outq,
                               float* __restrict__ outs, int ngroups) {
    int gid = blockIdx.x * (blockDim.x >> 6) + (threadIdx.x >> 6);
    if (gid >= ngroups) return;
    int lane = threadIdx.x & 63;
    unsigned int pv = *reinterpret_cast<const unsigned int*>(in + (size_t)gid * 128 + lane * 2);
    float v0 = __uint_as_float((pv & 0xFFFFu) << 16);
    float v1 = __uint_as_float(pv & 0xFFFF0000u);
    { float t0 = v0 + v1, t1 = v0 - v1; v0 = t0; v1 = t1; }
#pragma unroll
    for (int m = 1; m <= 32; m <<= 1) {
        float b0 = __shfl_xor(v0, m);
        float b1 = __shfl_xor(v1, m);
        if (lane & m) { v0 = b0 - v0; v1 = b1 - v1; }
        else          { v0 = v0 + b0; v1 = v1 + b1; }
    }
    const float s = 0.08838834764831843f;
    v0 *= s; v1 *= s;
    float am = fmaxf(fabsf(v0), fabsf(v1));
#pragma unroll
    for (int m = 1; m <= 32; m <<= 1) am = fmaxf(am, __shfl_xor(am, m));
    float inv = (am > 0.f) ? 127.0f / am : 0.f;
    int q0 = (int)rintf(v0 * inv);
    int q1 = (int)rintf(v1 * inv);
    unsigned short pk = (unsigned short)((q0 & 0xff) | ((q1 & 0xff) << 8));
    *reinterpret_cast<unsigned short*>(outq + (size_t)gid * 128 + lane * 2) = pk;
    if (lane == 0) outs[gid] = (am > 0.f) ? am / 127.0f : 1.0f;
}

// ---------- weight repack: int4-in-int32 -> int8 (EXACT: value-8 in [-8,7]) --------
__global__ void repack_w8(const int* __restrict__ Wq, signed char* __restrict__ W8, int total8) {
    int t = blockIdx.x * blockDim.x + threadIdx.x;
    if (t >= total8) return;
    size_t base = (size_t)t * 8;
    const int32x4* p = reinterpret_cast<const int32x4*>(Wq + base);
    int32x4 a = p[0], b = p[1];
    unsigned int lo = ((unsigned int)(unsigned char)(a.x - 8)) |
                      ((unsigned int)(unsigned char)(a.y - 8) << 8) |
                      ((unsigned int)(unsigned char)(a.z - 8) << 16) |
                      ((unsigned int)(unsigned char)(a.w - 8) << 24);
    unsigned int hi = ((unsigned int)(unsigned char)(b.x - 8)) |
                      ((unsigned int)(unsigned char)(b.y - 8) << 8) |
                      ((unsigned int)(unsigned char)(b.z - 8) << 16) |
                      ((unsigned int)(unsigned char)(b.w - 8) << 24);
    *reinterpret_cast<uint2*>(W8 + base) = make_uint2(lo, hi);
}

// =====================================================================================
// int8 256x256 GEMM, BK=128 (= one quant group), r4 skeleton: 2 K-tiles/iter, 8 phases,
// counted VMW(4) at ph4/ph8. Per K-tile staged: A 32KB (2 halves x 2 loads) + B 32KB +
// 2 scale loads (as[256], ws[256] f32 via gload_lds width 4) = 10 VMEM/wave.
// Ledger (hand-verified): at ph4, outstanding 14, VMW(4) retires the 10 of tile a+1
// (B prev ph7-8, A+sc ph1-2); at ph8 retires tile a+2's 10; B(next) stays in flight.
// MFMA: mfma_i32_16x16x64_i8; per phase one m-quadrant (2m x 4n x 2ksub = 16 MFMA);
// int32 acc exact per group; flush facc += as[row]*ws[col]*iacc after each phase.
// LDS rows = 128B; chunk c (16B) stored at c^(r&7) (T2, source-side), read (ks*4+kc)^(r&7).
// MODE 0: bf16 out; 1: h=silu(C)*acc in place (bf16); 2: f32 out.
// =====================================================================================

#define GBAR()  __builtin_amdgcn_s_barrier()
#define LGKM0() asm volatile("s_waitcnt lgkmcnt(0)" ::: "memory")
#define VMW(n)  asm volatile("s_waitcnt vmcnt(" #n ")" ::: "memory")
#define P1()    __builtin_amdgcn_s_setprio(1)
#define P0()    __builtin_amdgcn_s_setprio(0)

// stage one 16KB half-tile: mat 0=A(rows m0+), 1=B(rows n0+); h = M-half; kb in BYTES(=k)
#define STG8(src, row0, bb, mat, h, kb)                                                \
  { _Pragma("unroll")                                                                  \
    for (int l_ = 0; l_ < 2; ++l_) {                                                   \
      const int r_ = (h) * 128 + l_ * 64 + (tid >> 3);                                 \
      const int cg_ = (tid & 7) ^ (r_ & 7);                                            \
      const signed char* gp_ = (src) + (size_t)((row0) + r_) * K + (kb) + cg_ * 16;    \
      signed char* lp_ = lds8 + (bb) * 65536 + (mat) * 32768 +                         \
          ((h) * 128 + l_ * 64 + (wid << 3)) * 128;                                    \
      __builtin_amdgcn_global_load_lds((gmem_void*)gp_, (lds_void*)lp_, 16, 0, 0);     \
    } }

// stage scales for tile (group g): as rows m0+, ws rows n0+; 2 gload_lds width 4.
// each wave covers chunk (wid&3); waves 0-3 / 4-7 write duplicates (same data, benign).
#define STGS(bb, g)                                                                    \
  { const float* ap_ = AS + (size_t)(m0 + ((wid & 3) << 6) + lane) * Ksc + (g);        \
    __builtin_amdgcn_global_load_lds((gmem_void*)ap_,                                  \
        (lds_void*)&scl[bb][0][(wid & 3) << 6], 4, 0, 0);                              \
    const float* wp_ = WS + (size_t)(n0 + ((wid & 3) << 6) + lane) * Ksc + (g);        \
    __builtin_amdgcn_global_load_lds((gmem_void*)wp_,                                  \
        (lds_void*)&scl[bb][1][(wid & 3) << 6], 4, 0, 0); }

// A frags + a-scales for quadrant q of buffer bb
#define LDA8(bb, q)                                                                    \
  _Pragma("unroll")                                                                    \
  for (int f_ = 0; f_ < 2; ++f_) {                                                     \
    int r_ = wr * 128 + ((q) * 2 + f_) * 16 + (lane & 15);                             \
    _Pragma("unroll")                                                                  \
    for (int ks_ = 0; ks_ < 2; ++ks_)                                                  \
      af[f_][ks_] = *reinterpret_cast<const int32x4*>(lds8 + (bb) * 65536              \
          + r_ * 128 + (((ks_ * 4 + kc) ^ (r_ & 7)) << 4));                            \
    asv[f_] = *reinterpret_cast<const f32x4*>(                                         \
        &scl[bb][0][wr * 128 + ((q) * 2 + f_) * 16 + ((lane >> 4) << 2)]);             \
  }

// B frags (full K-tile) + w-scales of buffer bb
#define LDBW(bb)                                                                       \
  _Pragma("unroll")                                                                    \
  for (int ni_ = 0; ni_ < 4; ++ni_) {                                                  \
    int r_ = wc * 64 + ni_ * 16 + (lane & 15);                                         \
    _Pragma("unroll")                                                                  \
    for (int ks_ = 0; ks_ < 2; ++ks_)                                                  \
      bk[ni_][ks_] = *reinterpret_cast<const int32x4*>(lds8 + (bb) * 65536 + 32768     \
          + r_ * 128 + (((ks_ * 4 + kc) ^ (r_ & 7)) << 4));                            \
    wsv[ni_] = scl[bb][1][wc * 64 + ni_ * 16 + (lane & 15)];                           \
  }

#define MFI8()                                                                         \
  _Pragma("unroll")                                                                    \
  for (int f_ = 0; f_ < 2; ++f_)                                                       \
  _Pragma("unroll")                                                                    \
  for (int ni_ = 0; ni_ < 4; ++ni_)                                                    \
    iq[f_][ni_] = __builtin_amdgcn_mfma_i32_16x16x64_i8(af[f_][1], bk[ni_][1],         \
        __builtin_amdgcn_mfma_i32_16x16x64_i8(af[f_][0], bk[ni_][0],                   \
            (int32x4)0, 0, 0, 0), 0, 0, 0);

#define FLUSH(q)                                                                       \
  _Pragma("unroll")                                                                    \
  for (int f_ = 0; f_ < 2; ++f_)                                                       \
  _Pragma("unroll")                                                                    \
  for (int ni_ = 0; ni_ < 4; ++ni_)                                                    \
  _Pragma("unroll")                                                                    \
  for (int r_ = 0; r_ < 4; ++r_)                                                       \
    facc[(q) * 2 + f_][ni_][r_] += asv[f_][r_] * wsv[ni_] * (float)iq[f_][ni_][r_];

template<int MODE>
__global__ __launch_bounds__(512, 2)
void gemm_i8(const signed char* __restrict__ A, const float* __restrict__ AS,
             const signed char* __restrict__ W, const float* __restrict__ WS,
             void* __restrict__ C, int M, int N, int K)
{
    __shared__ __align__(16) signed char lds8[131072];   // 2 buf x (A 32KB | B 32KB)
    __shared__ __align__(16) float scl[2][2][256];       // [buf][as|ws][row]

    const int Ksc = K >> 7;                       // scale stride (groups per row)
    const int MT = M >> 8;
    const int nwg = gridDim.x;
    const int bid = blockIdx.x;
    const int cpx = nwg >> 3;
    const int wg  = (bid & 7) * cpx + (bid >> 3); // bijective XCD swizzle
    const int m0 = (wg % MT) << 8;
    const int n0 = (wg / MT) << 8;

    const int tid  = threadIdx.x;
    const int lane = tid & 63;
    const int wid  = tid >> 6;
    const int wr = wid >> 2;                      // 0..1 (M half)
    const int wc = wid & 3;                       // 0..3 (N quarter)
    const int kc = lane >> 4;                     // 16B k-chunk (0..3)

    f32x4 facc[8][4];
#pragma unroll
    for (int i = 0; i < 8; ++i)
#pragma unroll
        for (int j = 0; j < 4; ++j) facc[i][j] = (f32x4)0.0f;

    const int NT = K >> 7;                        // K-tiles of 128 (32 or 96)
    const int J  = NT >> 1;

    int32x4 af[2][2], bk[4][2], iq[2][4];
    f32x4 asv[2];
    float wsv[4];

    // ---- prologue: tile0 (A,B,scales) + tile1 B; retire tile0 (10), keep B(1) (4) ----
    STG8(A, m0, 0, 0, 0, 0); STG8(A, m0, 0, 0, 1, 0);
    STG8(W, n0, 0, 1, 0, 0); STG8(W, n0, 0, 1, 1, 0);
    STGS(0, 0);
    STG8(W, n0, 1, 1, 0, 128); STG8(W, n0, 1, 1, 1, 128);
    VMW(4);
    GBAR();

    for (int j = 0; j < J - 1; ++j) {
        const int a   = j << 1;
        const int kb1 = (a + 1) << 7;
        const int kb2 = (a + 2) << 7;
        const int kb3 = (a + 3) << 7;
        // ph1: tile a q0
        LDBW(0); LDA8(0, 0); STG8(A, m0, 1, 0, 0, kb1); STGS(1, a + 1);
        GBAR(); LGKM0(); P1(); MFI8(); P0(); FLUSH(0); GBAR();
        // ph2
        LDA8(0, 1); STG8(A, m0, 1, 0, 1, kb1);
        GBAR(); LGKM0(); P1(); MFI8(); P0(); FLUSH(1); GBAR();
        // ph3
        LDA8(0, 2); STG8(W, n0, 0, 1, 0, kb2);
        GBAR(); LGKM0(); P1(); MFI8(); P0(); FLUSH(2); GBAR();
        // ph4
        LDA8(0, 3); STG8(W, n0, 0, 1, 1, kb2);
        GBAR(); LGKM0(); P1(); MFI8(); P0(); FLUSH(3); VMW(4); GBAR();
        // ph5: tile a+1 q0
        LDBW(1); LDA8(1, 0); STG8(A, m0, 0, 0, 0, kb2); STGS(0, a + 2);
        GBAR(); LGKM0(); P1(); MFI8(); P0(); FLUSH(0); GBAR();
        // ph6
        LDA8(1, 1); STG8(A, m0, 0, 0, 1, kb2);
        GBAR(); LGKM0(); P1(); MFI8(); P0(); FLUSH(1); GBAR();
        // ph7
        LDA8(1, 2); STG8(W, n0, 1, 1, 0, kb3);
        GBAR(); LGKM0(); P1(); MFI8(); P0(); FLUSH(2); GBAR();
        // ph8
        LDA8(1, 3); STG8(W, n0, 1, 1, 1, kb3);
        GBAR(); LGKM0(); P1(); MFI8(); P0(); FLUSH(3); VMW(4); GBAR();
    }

    // ---- peeled final iteration (tiles NT-2, NT-1) ----
    {
        const int kb1 = (NT - 1) << 7;
        LDBW(0); LDA8(0, 0); STG8(A, m0, 1, 0, 0, kb1); STGS(1, NT - 1);
        GBAR(); LGKM0(); P1(); MFI8(); P0(); FLUSH(0); GBAR();
        LDA8(0, 1); STG8(A, m0, 1, 0, 1, kb1);
        GBAR(); LGKM0(); P1(); MFI8(); P0(); FLUSH(1); GBAR();
        LDA8(0, 2);
        GBAR(); LGKM0(); P1(); MFI8(); P0(); FLUSH(2); GBAR();
        LDA8(0, 3);
        GBAR(); LGKM0(); P1(); MFI8(); P0(); FLUSH(3); VMW(0); GBAR();
        LDBW(1); LDA8(1, 0);
        GBAR(); LGKM0(); P1(); MFI8(); P0(); FLUSH(0); GBAR();
        LDA8(1, 1);
        GBAR(); LGKM0(); P1(); MFI8(); P0(); FLUSH(1); GBAR();
        LDA8(1, 2);
        GBAR(); LGKM0(); P1(); MFI8(); P0(); FLUSH(2); GBAR();
        LDA8(1, 3);
        GBAR(); LGKM0(); P1(); MFI8(); P0(); FLUSH(3);
    }

    // ---- epilogue: D-frag col=lane&15, row=(lane>>4)*4+r ----
#pragma unroll
    for (int mi = 0; mi < 8; ++mi)
#pragma unroll
        for (int ni = 0; ni < 4; ++ni) {
            const int col = n0 + (wc << 6) + ni * 16 + (lane & 15);
#pragma unroll
            for (int r = 0; r < 4; ++r) {
                const int row = m0 + (wr << 7) + mi * 16 + ((lane >> 4) << 2) + r;
                const size_t idx = (size_t)row * N + col;
                if (MODE == 2) {
                    ((float*)C)[idx] = facc[mi][ni][r];
                } else if (MODE == 0) {
                    ((unsigned short*)C)[idx] = f2bf(facc[mi][ni][r]);
                } else {
                    float g = bf2f(((unsigned short*)C)[idx]);
                    float u = facc[mi][ni][r];
                    float h = (g / (1.0f + __expf(-g))) * u;
                    ((unsigned short*)C)[idx] = f2bf(h);
                }
            }
        }
}

// ============== FALLBACK (round-1 verified): bf16 had + in-loop dequant =============
__global__ void had_f32_to_bf16(const float* __restrict__ in, unsigned short* __restrict__ out,
                                int ngroups) {
    int gid = blockIdx.x * (blockDim.x >> 6) + (threadIdx.x >> 6);
    if (gid >= ngroups) return;
    int lane = threadIdx.x & 63;
    const float2 v2 = *reinterpret_cast<const float2*>(in + (size_t)gid * 128 + lane * 2);
    float v0 = v2.x, v1 = v2.y;
    { float t0 = v0 + v1, t1 = v0 - v1; v0 = t0; v1 = t1; }
#pragma unroll
    for (int m = 1; m <= 32; m <<= 1) {
        float b0 = __shfl_xor(v0, m);
        float b1 = __shfl_xor(v1, m);
        if (lane & m) { v0 = b0 - v0; v1 = b1 - v1; }
        else          { v0 = v0 + b0; v1 = v1 + b1; }
    }
    const float s = 0.08838834764831843f;
    unsigned int o = (unsigned int)f2bf(v0 * s) | ((unsigned int)f2bf(v1 * s) << 16);
    *reinterpret_cast<unsigned int*>(out + (size_t)gid * 128 + lane * 2) = o;
}

__global__ void had_bf16_inplace(unsigned short* __restrict__ buf, int ngroups) {
    int gid = blockIdx.x * (blockDim.x >> 6) + (threadIdx.x >> 6);
    if (gid >= ngroups) return;
    int lane = threadIdx.x & 63;
    unsigned int pv = *reinterpret_cast<const unsigned int*>(buf + (size_t)gid * 128 + lane * 2);
    float v0 = __uint_as_float((pv & 0xFFFFu) << 16);
    float v1 = __uint_as_float(pv & 0xFFFF0000u);
    { float t0 = v0 + v1, t1 = v0 - v1; v0 = t0; v1 = t1; }
#pragma unroll
    for (int m = 1; m <= 32; m <<= 1) {
        float b0 = __shfl_xor(v0, m);
        float b1 = __shfl_xor(v1, m);
        if (lane & m) { v0 = b0 - v0; v1 = b1 - v1; }
        else          { v0 = v0 + b0; v1 = v1 + b1; }
    }
    const float s = 0.08838834764831843f;
    unsigned int o = (unsigned int)f2bf(v0 * s) | ((unsigned int)f2bf(v1 * s) << 16);
    *reinterpret_cast<unsigned int*>(buf + (size_t)gid * 128 + lane * 2) = o;
}

__global__ __launch_bounds__(256, 2)
void gemm_gateup_fb(const unsigned short* __restrict__ Xr,
                    const int* __restrict__ Wg, const float* __restrict__ Sg,
                    const int* __restrict__ Wu, const float* __restrict__ Su,
                    unsigned short* __restrict__ H)
{
    __shared__ __align__(16) unsigned short lA [128 * 64];
    __shared__ __align__(16) unsigned short lBg[128 * 64];
    __shared__ __align__(16) unsigned short lBu[128 * 64];
    const int MT = T_DIM / 128;
    const int bid = blockIdx.x;
    const int m0 = (bid % MT) * 128;
    const int n0 = (bid / MT) * 128;
    const int tid  = threadIdx.x;
    const int lane = tid & 63;
    const int wid  = tid >> 6;
    const int wr = wid >> 1, wc = wid & 1;
    f32x4 accG[4][4], accU[4][4];
#pragma unroll
    for (int i = 0; i < 4; ++i)
#pragma unroll
        for (int j = 0; j < 4; ++j) { accG[i][j] = (f32x4)0.0f; accU[i][j] = (f32x4)0.0f; }
    const int arow = lane >> 3;
    const int acol = (lane & 7) * 8;
    const int SStride = D_DIM / GRP;
    for (int k0 = 0; k0 < D_DIM; k0 += 64) {
        __syncthreads();
#pragma unroll
        for (int it = 0; it < 4; ++it) {
            int chunk = wid * 4 + it;
            const unsigned short* gp = Xr + (size_t)(m0 + chunk * 8 + arow) * D_DIM + k0 + acol;
            __builtin_amdgcn_global_load_lds((gmem_void*)gp, (lds_void*)(lA + chunk * 512), 16, 0, 0);
        }
        const int g = k0 >> 7;
#pragma unroll
        for (int i = 0; i < 8; ++i) {
            int linear = i * 1024 + tid * 4;
            int r = linear >> 6;
            int c = linear & 63;
            const int32x4 wg = *reinterpret_cast<const int32x4*>(Wg + (size_t)(n0 + r) * D_DIM + k0 + c);
            const int32x4 wu = *reinterpret_cast<const int32x4*>(Wu + (size_t)(n0 + r) * D_DIM + k0 + c);
            float scg = Sg[(size_t)(n0 + r) * SStride + g];
            float scu = Su[(size_t)(n0 + r) * SStride + g];
            unsigned int g01 = (unsigned int)f2bf((float)(wg.x - 8) * scg) | ((unsigned int)f2bf((float)(wg.y - 8) * scg) << 16);
            unsigned int g23 = (unsigned int)f2bf((float)(wg.z - 8) * scg) | ((unsigned int)f2bf((float)(wg.w - 8) * scg) << 16);
            unsigned int u01 = (unsigned int)f2bf((float)(wu.x - 8) * scu) | ((unsigned int)f2bf((float)(wu.y - 8) * scu) << 16);
            unsigned int u23 = (unsigned int)f2bf((float)(wu.z - 8) * scu) | ((unsigned int)f2bf((float)(wu.w - 8) * scu) << 16);
            *reinterpret_cast<uint2*>(lBg + r * 64 + c) = make_uint2(g01, g23);
            *reinterpret_cast<uint2*>(lBu + r * 64 + c) = make_uint2(u01, u23);
        }
        __syncthreads();
#pragma unroll
        for (int ks = 0; ks < 2; ++ks) {
            const int koff = ks * 32 + (lane >> 4) * 8;
            bf16x8 af[4], bg[4], bu[4];
#pragma unroll
            for (int mi = 0; mi < 4; ++mi)
                af[mi] = *reinterpret_cast<const bf16x8*>(lA + (wr * 64 + mi * 16 + (lane & 15)) * 64 + koff);
#pragma unroll
            for (int ni = 0; ni < 4; ++ni) {
                bg[ni] = *reinterpret_cast<const bf16x8*>(lBg + (wc * 64 + ni * 16 + (lane & 15)) * 64 + koff);
                bu[ni] = *reinterpret_cast<const bf16x8*>(lBu + (wc * 64 + ni * 16 + (lane & 15)) * 64 + koff);
            }
#pragma unroll
            for (int mi = 0; mi < 4; ++mi)
#pragma unroll
                for (int ni = 0; ni < 4; ++ni) {
                    accG[mi][ni] = __builtin_amdgcn_mfma_f32_16x16x32_bf16(af[mi], bg[ni], accG[mi][ni], 0, 0, 0);
                    accU[mi][ni] = __builtin_amdgcn_mfma_f32_16x16x32_bf16(af[mi], bu[ni], accU[mi][ni], 0, 0, 0);
                }
        }
    }
#pragma unroll
    for (int mi = 0; mi < 4; ++mi)
#pragma unroll
        for (int ni = 0; ni < 4; ++ni) {
            const int col = n0 + wc * 64 + ni * 16 + (lane & 15);
#pragma unroll
            for (int r = 0; r < 4; ++r) {
                const int row = m0 + wr * 64 + mi * 16 + (lane >> 4) * 4 + r;
                float gv = accG[mi][ni][r];
                float uv = accU[mi][ni][r];
                float hv = (gv / (1.0f + __expf(-gv))) * uv;
                H[(size_t)row * I_DIM + col] = f2bf(hv);
            }
        }
}

__global__ __launch_bounds__(256, 2)
void gemm_down_fb(const unsigned short* __restrict__ Hr,
                  const int* __restrict__ Wd, const float* __restrict__ Sd,
                  float* __restrict__ Out)
{
    __shared__ __align__(16) unsigned short lA[128 * 64];
    __shared__ __align__(16) unsigned short lB[128 * 64];
    const int MT = T_DIM / 128;
    const int bid = blockIdx.x;
    const int m0 = (bid % MT) * 128;
    const int n0 = (bid / MT) * 128;
    const int tid  = threadIdx.x;
    const int lane = tid & 63;
    const int wid  = tid >> 6;
    const int wr = wid >> 1, wc = wid & 1;
    f32x4 acc[4][4];
#pragma unroll
    for (int i = 0; i < 4; ++i)
#pragma unroll
        for (int j = 0; j < 4; ++j) acc[i][j] = (f32x4)0.0f;
    const int arow = lane >> 3;
    const int acol = (lane & 7) * 8;
    const int SStride = I_DIM / GRP;
    for (int k0 = 0; k0 < I_DIM; k0 += 64) {
        __syncthreads();
#pragma unroll
        for (int it = 0; it < 4; ++it) {
            int chunk = wid * 4 + it;
            const unsigned short* gp = Hr + (size_t)(m0 + chunk * 8 + arow) * I_DIM + k0 + acol;
            __builtin_amdgcn_global_load_lds((gmem_void*)gp, (lds_void*)(lA + chunk * 512), 16, 0, 0);
        }
        const int g = k0 >> 7;
#pragma unroll
        for (int i = 0; i < 8; ++i) {
            int linear = i * 1024 + tid * 4;
            int r = linear >> 6;
            int c = linear & 63;
            const int32x4 wd = *reinterpret_cast<const int32x4*>(Wd + (size_t)(n0 + r) * I_DIM + k0 + c);
            float sc = Sd[(size_t)(n0 + r) * SStride + g];
            unsigned int d01 = (unsigned int)f2bf((float)(wd.x - 8) * sc) | ((unsigned int)f2bf((float)(wd.y - 8) * sc) << 16);
            unsigned int d23 = (unsigned int)f2bf((float)(wd.z - 8) * sc) | ((unsigned int)f2bf((float)(wd.w - 8) * sc) << 16);
            *reinterpret_cast<uint2*>(lB + r * 64 + c) = make_uint2(d01, d23);
        }
        __syncthreads();
#pragma unroll
        for (int ks = 0; ks < 2; ++ks) {
            const int koff = ks * 32 + (lane >> 4) * 8;
            bf16x8 af[4], bfr[4];
#pragma unroll
            for (int mi = 0; mi < 4; ++mi)
                af[mi] = *reinterpret_cast<const bf16x8*>(lA + (wr * 64 + mi * 16 + (lane & 15)) * 64 + koff);
#pragma unroll
            for (int ni = 0; ni < 4; ++ni)
                bfr[ni] = *reinterpret_cast<const bf16x8*>(lB + (wc * 64 + ni * 16 + (lane & 15)) * 64 + koff);
#pragma unroll
            for (int mi = 0; mi < 4; ++mi)
#pragma unroll
                for (int ni = 0; ni < 4; ++ni)
                    acc[mi][ni] = __builtin_amdgcn_mfma_f32_16x16x32_bf16(af[mi], bfr[ni], acc[mi][ni], 0, 0, 0);
        }
    }
#pragma unroll
    for (int mi = 0; mi < 4; ++mi)
#pragma unroll
        for (int ni = 0; ni < 4; ++ni) {
            const int col = n0 + wc * 64 + ni * 16 + (lane & 15);
#pragma unroll
            for (int r = 0; r < 4; ++r) {
                const int row = m0 + wr * 64 + mi * 16 + (lane >> 4) * 4 + r;
                Out[(size_t)row * D_DIM + col] = acc[mi][ni][r];
            }
        }
}

extern "C" void kernel_launch(void* const* d_in, const int* in_sizes, int n_in,
                              void* d_out, int out_size, void* d_ws, size_t ws_size,
                              hipStream_t stream) {
    const float* x       = (const float*)d_in[0];
    const int*   wq_gate = (const int*)d_in[1];
    const float* s_gate  = (const float*)d_in[2];
    const int*   wq_up   = (const int*)d_in[3];
    const float* s_up    = (const float*)d_in[4];
    const int*   wq_down = (const int*)d_in[5];
    const float* s_down  = (const float*)d_in[6];
    float* out = (float*)d_out;

    const size_t XR_E = (size_t)T_DIM * D_DIM;      // 16.8M elems
    const size_t H_E  = (size_t)T_DIM * I_DIM;      // 50.3M
    const size_t W_E  = (size_t)I_DIM * D_DIM;      // 50.3M
    const size_t need = (XR_E + H_E + 2 * W_E) * 2; // 335.5 MB (same check as before)

    char* base = (char*)d_ws;

    if (ws_size >= need) {
        // layout: xq i8 | xs f32 | h bf16 | hq i8 | hs f32 | w8a | w8b   (~258 MB)
        signed char*    xq = (signed char*)base;
        float*          xs = (float*)(base + XR_E);
        unsigned short* h  = (unsigned short*)(base + XR_E + (XR_E / 128) * 4);
        signed char*    hq = (signed char*)((char*)h + H_E * 2);
        float*          hs = (float*)((char*)hq + H_E);
        signed char*    w8a = (signed char*)((char*)hs + (H_E / 128) * 4);
        signed char*    w8b = w8a + W_E;

        // 1) xq,xs = int8-quant(hadamard(x))
        {
            int ngroups = (int)(XR_E / 128);
            had_f32_to_i8<<<dim3(ngroups / 4), dim3(256), 0, stream>>>(x, xq, xs, ngroups);
        }
        // 2) repack gate & up weights -> int8 (exact)
        int total8 = (int)(W_E / 8);
        repack_w8<<<dim3((total8 + 255) / 256), dim3(256), 0, stream>>>(wq_gate, w8a, total8);
        repack_w8<<<dim3((total8 + 255) / 256), dim3(256), 0, stream>>>(wq_up,   w8b, total8);
        // 3) gate = xq @ w8a^T (scaled) -> h bf16
        gemm_i8<0><<<dim3((T_DIM / 256) * (I_DIM / 256)), dim3(512), 0, stream>>>(
            xq, xs, w8a, s_gate, (void*)h, T_DIM, I_DIM, D_DIM);
        // 4) h = silu(gate) * (xq @ w8b^T)
        gemm_i8<1><<<dim3((T_DIM / 256) * (I_DIM / 256)), dim3(512), 0, stream>>>(
            xq, xs, w8b, s_up, (void*)h, T_DIM, I_DIM, D_DIM);
        // 5) hq,hs = int8-quant(hadamard(h))
        {
            int ngroups = (int)(H_E / 128);
            had_bf16_to_i8<<<dim3(ngroups / 4), dim3(256), 0, stream>>>(h, hq, hs, ngroups);
        }
        // 6) repack down weights (reuse w8a)
        repack_w8<<<dim3((total8 + 255) / 256), dim3(256), 0, stream>>>(wq_down, w8a, total8);
        // 7) out = hq @ w8a^T (scaled), f32
        gemm_i8<2><<<dim3((T_DIM / 256) * (D_DIM / 256)), dim3(512), 0, stream>>>(
            hq, hs, w8a, s_down, (void*)out, T_DIM, D_DIM, I_DIM);
    } else {
        // fallback: round-1 verified bf16 path
        unsigned short* xr = (unsigned short*)d_ws;
        unsigned short* h  = xr + XR_E;
        {
            int ngroups = (int)(XR_E / 128);
            had_f32_to_bf16<<<dim3(ngroups / 4), dim3(256), 0, stream>>>(x, xr, ngroups);
        }
        gemm_gateup_fb<<<dim3((T_DIM / 128) * (I_DIM / 128)), dim3(256), 0, stream>>>(
            xr, wq_gate, s_gate, wq_up, s_up, h);
        {
            int ngroups = (int)(H_E / 128);
            had_bf16_inplace<<<dim3(ngroups / 4), dim3(256), 0, stream>>>(h, ngroups);
        }
        gemm_down_fb<<<dim3((T_DIM / 128) * (D_DIM / 128)), dim3(256), 0, stream>>>(
            h, wq_down, s_down, out);
    }
}

// Round 16
// 7014.232 us; speedup vs baseline: 1.0004x; 1.0004x over previous
//
#include <hip/hip_runtime.h>
#include <hip/hip_bf16.h>
#include <cstdint>

#define T_DIM 4096
#define D_DIM 4096
#define I_DIM 12288
#define GRP   128

typedef __attribute__((ext_vector_type(8))) short bf16x8;
typedef __attribute__((ext_vector_type(4))) float f32x4;
typedef __attribute__((ext_vector_type(4))) int   int32x4;

typedef __attribute__((address_space(3))) void lds_void;
typedef const __attribute__((address_space(1))) void gmem_void;

static __device__ __forceinline__ unsigned short f2bf(float f) {
    unsigned int u = __float_as_uint(f);
    u += 0x7FFFu + ((u >> 16) & 1u);
    return (unsigned short)(u >> 16);
}
static __device__ __forceinline__ float bf2f(unsigned short b) {
    return __uint_as_float(((unsigned int)b) << 16);
}

// ---------- Hadamard + int8 quant (per-128-group scale), one wave per group --------
__global__ void had_f32_to_i8(const float* __restrict__ in, signed char* __restrict__ outq,
                              float* __restrict__ outs, int ngroups) {
    int gid = blockIdx.x * (blockDim.x >> 6) + (threadIdx.x >> 6);
    if (gid >= ngroups) return;
    int lane = threadIdx.x & 63;
    const float2 v2 = *reinterpret_cast<const float2*>(in + (size_t)gid * 128 + lane * 2);
    float v0 = v2.x, v1 = v2.y;
    { float t0 = v0 + v1, t1 = v0 - v1; v0 = t0; v1 = t1; }
#pragma unroll
    for (int m = 1; m <= 32; m <<= 1) {
        float b0 = __shfl_xor(v0, m);
        float b1 = __shfl_xor(v1, m);
        if (lane & m) { v0 = b0 - v0; v1 = b1 - v1; }
        else          { v0 = v0 + b0; v1 = v1 + b1; }
    }
    const float s = 0.08838834764831843f;  // 1/sqrt(128)
    v0 *= s; v1 *= s;
    float am = fmaxf(fabsf(v0), fabsf(v1));
#pragma unroll
    for (int m = 1; m <= 32; m <<= 1) am = fmaxf(am, __shfl_xor(am, m));
    float inv = (am > 0.f) ? 127.0f / am : 0.f;
    int q0 = (int)rintf(v0 * inv);
    int q1 = (int)rintf(v1 * inv);
    unsigned short pk = (unsigned short)((q0 & 0xff) | ((q1 & 0xff) << 8));
    *reinterpret_cast<unsigned short*>(outq + (size_t)gid * 128 + lane * 2) = pk;
    if (lane == 0) outs[gid] = (am > 0.f) ? am / 127.0f : 1.0f;
}

__global__ void had_bf16_to_i8(const unsigned short* __restrict__ in, signed char* __restrict__ outq,
                               float* __restrict__ outs, int ngroups) {
    int gid = blockIdx.x * (blockDim.x >> 6) + (threadIdx.x >> 6);
    if (gid >= ngroups) return;
    int lane = threadIdx.x & 63;
    unsigned int pv = *reinterpret_cast<const unsigned int*>(in + (size_t)gid * 128 + lane * 2);
    float v0 = __uint_as_float((pv & 0xFFFFu) << 16);
    float v1 = __uint_as_float(pv & 0xFFFF0000u);
    { float t0 = v0 + v1, t1 = v0 - v1; v0 = t0; v1 = t1; }
#pragma unroll
    for (int m = 1; m <= 32; m <<= 1) {
        float b0 = __shfl_xor(v0, m);
        float b1 = __shfl_xor(v1, m);
        if (lane & m) { v0 = b0 - v0; v1 = b1 - v1; }
        else          { v0 = v0 + b0; v1 = v1 + b1; }
    }
    const float s = 0.08838834764831843f;
    v0 *= s; v1 *= s;
    float am = fmaxf(fabsf(v0), fabsf(v1));
#pragma unroll
    for (int m = 1; m <= 32; m <<= 1) am = fmaxf(am, __shfl_xor(am, m));
    float inv = (am > 0.f) ? 127.0f / am : 0.f;
    int q0 = (int)rintf(v0 * inv);
    int q1 = (int)rintf(v1 * inv);
    unsigned short pk = (unsigned short)((q0 & 0xff) | ((q1 & 0xff) << 8));
    *reinterpret_cast<unsigned short*>(outq + (size_t)gid * 128 + lane * 2) = pk;
    if (lane == 0) outs[gid] = (am > 0.f) ? am / 127.0f : 1.0f;
}

// ---------- weight repack: int4-in-int32 -> int8 (EXACT: value-8 in [-8,7]) --------
__global__ void repack_w8(const int* __restrict__ Wq, signed char* __restrict__ W8, int total8) {
    int t = blockIdx.x * blockDim.x + threadIdx.x;
    if (t >= total8) return;
    size_t base = (size_t)t * 8;
    const int32x4* p = reinterpret_cast<const int32x4*>(Wq + base);
    int32x4 a = p[0], b = p[1];
    unsigned int lo = ((unsigned int)(unsigned char)(a.x - 8)) |
                      ((unsigned int)(unsigned char)(a.y - 8) << 8) |
                      ((unsigned int)(unsigned char)(a.z - 8) << 16) |
                      ((unsigned int)(unsigned char)(a.w - 8) << 24);
    unsigned int hi = ((unsigned int)(unsigned char)(b.x - 8)) |
                      ((unsigned int)(unsigned char)(b.y - 8) << 8) |
                      ((unsigned int)(unsigned char)(b.z - 8) << 16) |
                      ((unsigned int)(unsigned char)(b.w - 8) << 24);
    *reinterpret_cast<uint2*>(W8 + base) = make_uint2(lo, hi);
}

// =====================================================================================
// int8 256x256 GEMM, BK=128 (= one quant group), r4 skeleton, NUMERICS VERIFIED r15
// (absmax 0.4375). r15 regression: __launch_bounds__(512,2) -> 128-reg/wave budget ->
// facc (128 VALU-updated f32) spilled -> 4.5GB scratch writes, MfmaUtil 3%.
// FIX: __launch_bounds__(512,1) -> 256-reg budget; facc VGPR-resident, iq in AGPR.
// Everything else identical to r15 (ledger/swizzle/liveness hand-verified there).
// =====================================================================================

#define GBAR()  __builtin_amdgcn_s_barrier()
#define LGKM0() asm volatile("s_waitcnt lgkmcnt(0)" ::: "memory")
#define VMW(n)  asm volatile("s_waitcnt vmcnt(" #n ")" ::: "memory")
#define P1()    __builtin_amdgcn_s_setprio(1)
#define P0()    __builtin_amdgcn_s_setprio(0)

// stage one 16KB half-tile: mat 0=A(rows m0+), 1=B(rows n0+); h = M-half; kb in BYTES(=k)
#define STG8(src, row0, bb, mat, h, kb)                                                \
  { _Pragma("unroll")                                                                  \
    for (int l_ = 0; l_ < 2; ++l_) {                                                   \
      const int r_ = (h) * 128 + l_ * 64 + (tid >> 3);                                 \
      const int cg_ = (tid & 7) ^ (r_ & 7);                                            \
      const signed char* gp_ = (src) + (size_t)((row0) + r_) * K + (kb) + cg_ * 16;    \
      signed char* lp_ = lds8 + (bb) * 65536 + (mat) * 32768 +                         \
          ((h) * 128 + l_ * 64 + (wid << 3)) * 128;                                    \
      __builtin_amdgcn_global_load_lds((gmem_void*)gp_, (lds_void*)lp_, 16, 0, 0);     \
    } }

// stage scales for tile (group g): as rows m0+, ws rows n0+; 2 gload_lds width 4.
#define STGS(bb, g)                                                                    \
  { const float* ap_ = AS + (size_t)(m0 + ((wid & 3) << 6) + lane) * Ksc + (g);        \
    __builtin_amdgcn_global_load_lds((gmem_void*)ap_,                                  \
        (lds_void*)&scl[bb][0][(wid & 3) << 6], 4, 0, 0);                              \
    const float* wp_ = WS + (size_t)(n0 + ((wid & 3) << 6) + lane) * Ksc + (g);        \
    __builtin_amdgcn_global_load_lds((gmem_void*)wp_,                                  \
        (lds_void*)&scl[bb][1][(wid & 3) << 6], 4, 0, 0); }

// A frags + a-scales for quadrant q of buffer bb
#define LDA8(bb, q)                                                                    \
  _Pragma("unroll")                                                                    \
  for (int f_ = 0; f_ < 2; ++f_) {                                                     \
    int r_ = wr * 128 + ((q) * 2 + f_) * 16 + (lane & 15);                             \
    _Pragma("unroll")                                                                  \
    for (int ks_ = 0; ks_ < 2; ++ks_)                                                  \
      af[f_][ks_] = *reinterpret_cast<const int32x4*>(lds8 + (bb) * 65536              \
          + r_ * 128 + (((ks_ * 4 + kc) ^ (r_ & 7)) << 4));                            \
    asv[f_] = *reinterpret_cast<const f32x4*>(                                         \
        &scl[bb][0][wr * 128 + ((q) * 2 + f_) * 16 + ((lane >> 4) << 2)]);             \
  }

// B frags (full K-tile) + w-scales of buffer bb
#define LDBW(bb)                                                                       \
  _Pragma("unroll")                                                                    \
  for (int ni_ = 0; ni_ < 4; ++ni_) {                                                  \
    int r_ = wc * 64 + ni_ * 16 + (lane & 15);                                         \
    _Pragma("unroll")                                                                  \
    for (int ks_ = 0; ks_ < 2; ++ks_)                                                  \
      bk[ni_][ks_] = *reinterpret_cast<const int32x4*>(lds8 + (bb) * 65536 + 32768     \
          + r_ * 128 + (((ks_ * 4 + kc) ^ (r_ & 7)) << 4));                            \
    wsv[ni_] = scl[bb][1][wc * 64 + ni_ * 16 + (lane & 15)];                           \
  }

#define MFI8()                                                                         \
  _Pragma("unroll")                                                                    \
  for (int f_ = 0; f_ < 2; ++f_)                                                       \
  _Pragma("unroll")                                                                    \
  for (int ni_ = 0; ni_ < 4; ++ni_)                                                    \
    iq[f_][ni_] = __builtin_amdgcn_mfma_i32_16x16x64_i8(af[f_][1], bk[ni_][1],         \
        __builtin_amdgcn_mfma_i32_16x16x64_i8(af[f_][0], bk[ni_][0],                   \
            (int32x4)0, 0, 0, 0), 0, 0, 0);

#define FLUSH(q)                                                                       \
  _Pragma("unroll")                                                                    \
  for (int f_ = 0; f_ < 2; ++f_)                                                       \
  _Pragma("unroll")                                                                    \
  for (int ni_ = 0; ni_ < 4; ++ni_)                                                    \
  _Pragma("unroll")                                                                    \
  for (int r_ = 0; r_ < 4; ++r_)                                                       \
    facc[(q) * 2 + f_][ni_][r_] += asv[f_][r_] * wsv[ni_] * (float)iq[f_][ni_][r_];

template<int MODE>
__global__ __launch_bounds__(512, 1)
void gemm_i8(const signed char* __restrict__ A, const float* __restrict__ AS,
             const signed char* __restrict__ W, const float* __restrict__ WS,
             void* __restrict__ C, int M, int N, int K)
{
    __shared__ __align__(16) signed char lds8[131072];   // 2 buf x (A 32KB | B 32KB)
    __shared__ __align__(16) float scl[2][2][256];       // [buf][as|ws][row]

    const int Ksc = K >> 7;                       // scale stride (groups per row)
    const int MT = M >> 8;
    const int nwg = gridDim.x;
    const int bid = blockIdx.x;
    const int cpx = nwg >> 3;
    const int wg  = (bid & 7) * cpx + (bid >> 3); // bijective XCD swizzle
    const int m0 = (wg % MT) << 8;
    const int n0 = (wg / MT) << 8;

    const int tid  = threadIdx.x;
    const int lane = tid & 63;
    const int wid  = tid >> 6;
    const int wr = wid >> 2;                      // 0..1 (M half)
    const int wc = wid & 3;                       // 0..3 (N quarter)
    const int kc = lane >> 4;                     // 16B k-chunk (0..3)

    f32x4 facc[8][4];
#pragma unroll
    for (int i = 0; i < 8; ++i)
#pragma unroll
        for (int j = 0; j < 4; ++j) facc[i][j] = (f32x4)0.0f;

    const int NT = K >> 7;                        // K-tiles of 128 (32 or 96)
    const int J  = NT >> 1;

    int32x4 af[2][2], bk[4][2], iq[2][4];
    f32x4 asv[2];
    float wsv[4];

    // ---- prologue: tile0 (A,B,scales) + tile1 B; retire tile0 (10), keep B(1) (4) ----
    STG8(A, m0, 0, 0, 0, 0); STG8(A, m0, 0, 0, 1, 0);
    STG8(W, n0, 0, 1, 0, 0); STG8(W, n0, 0, 1, 1, 0);
    STGS(0, 0);
    STG8(W, n0, 1, 1, 0, 128); STG8(W, n0, 1, 1, 1, 128);
    VMW(4);
    GBAR();

    for (int j = 0; j < J - 1; ++j) {
        const int a   = j << 1;
        const int kb1 = (a + 1) << 7;
        const int kb2 = (a + 2) << 7;
        const int kb3 = (a + 3) << 7;
        // ph1: tile a q0
        LDBW(0); LDA8(0, 0); STG8(A, m0, 1, 0, 0, kb1); STGS(1, a + 1);
        GBAR(); LGKM0(); P1(); MFI8(); P0(); FLUSH(0); GBAR();
        // ph2
        LDA8(0, 1); STG8(A, m0, 1, 0, 1, kb1);
        GBAR(); LGKM0(); P1(); MFI8(); P0(); FLUSH(1); GBAR();
        // ph3
        LDA8(0, 2); STG8(W, n0, 0, 1, 0, kb2);
        GBAR(); LGKM0(); P1(); MFI8(); P0(); FLUSH(2); GBAR();
        // ph4
        LDA8(0, 3); STG8(W, n0, 0, 1, 1, kb2);
        GBAR(); LGKM0(); P1(); MFI8(); P0(); FLUSH(3); VMW(4); GBAR();
        // ph5: tile a+1 q0
        LDBW(1); LDA8(1, 0); STG8(A, m0, 0, 0, 0, kb2); STGS(0, a + 2);
        GBAR(); LGKM0(); P1(); MFI8(); P0(); FLUSH(0); GBAR();
        // ph6
        LDA8(1, 1); STG8(A, m0, 0, 0, 1, kb2);
        GBAR(); LGKM0(); P1(); MFI8(); P0(); FLUSH(1); GBAR();
        // ph7
        LDA8(1, 2); STG8(W, n0, 1, 1, 0, kb3);
        GBAR(); LGKM0(); P1(); MFI8(); P0(); FLUSH(2); GBAR();
        // ph8
        LDA8(1, 3); STG8(W, n0, 1, 1, 1, kb3);
        GBAR(); LGKM0(); P1(); MFI8(); P0(); FLUSH(3); VMW(4); GBAR();
    }

    // ---- peeled final iteration (tiles NT-2, NT-1) ----
    {
        const int kb1 = (NT - 1) << 7;
        LDBW(0); LDA8(0, 0); STG8(A, m0, 1, 0, 0, kb1); STGS(1, NT - 1);
        GBAR(); LGKM0(); P1(); MFI8(); P0(); FLUSH(0); GBAR();
        LDA8(0, 1); STG8(A, m0, 1, 0, 1, kb1);
        GBAR(); LGKM0(); P1(); MFI8(); P0(); FLUSH(1); GBAR();
        LDA8(0, 2);
        GBAR(); LGKM0(); P1(); MFI8(); P0(); FLUSH(2); GBAR();
        LDA8(0, 3);
        GBAR(); LGKM0(); P1(); MFI8(); P0(); FLUSH(3); VMW(0); GBAR();
        LDBW(1); LDA8(1, 0);
        GBAR(); LGKM0(); P1(); MFI8(); P0(); FLUSH(0); GBAR();
        LDA8(1, 1);
        GBAR(); LGKM0(); P1(); MFI8(); P0(); FLUSH(1); GBAR();
        LDA8(1, 2);
        GBAR(); LGKM0(); P1(); MFI8(); P0(); FLUSH(2); GBAR();
        LDA8(1, 3);
        GBAR(); LGKM0(); P1(); MFI8(); P0(); FLUSH(3);
    }

    // ---- epilogue: D-frag col=lane&15, row=(lane>>4)*4+r ----
#pragma unroll
    for (int mi = 0; mi < 8; ++mi)
#pragma unroll
        for (int ni = 0; ni < 4; ++ni) {
            const int col = n0 + (wc << 6) + ni * 16 + (lane & 15);
#pragma unroll
            for (int r = 0; r < 4; ++r) {
                const int row = m0 + (wr << 7) + mi * 16 + ((lane >> 4) << 2) + r;
                const size_t idx = (size_t)row * N + col;
                if (MODE == 2) {
                    ((float*)C)[idx] = facc[mi][ni][r];
                } else if (MODE == 0) {
                    ((unsigned short*)C)[idx] = f2bf(facc[mi][ni][r]);
                } else {
                    float g = bf2f(((unsigned short*)C)[idx]);
                    float u = facc[mi][ni][r];
                    float h = (g / (1.0f + __expf(-g))) * u;
                    ((unsigned short*)C)[idx] = f2bf(h);
                }
            }
        }
}

// ============== FALLBACK (round-1 verified): bf16 had + in-loop dequant =============
__global__ void had_f32_to_bf16(const float* __restrict__ in, unsigned short* __restrict__ out,
                                int ngroups) {
    int gid = blockIdx.x * (blockDim.x >> 6) + (threadIdx.x >> 6);
    if (gid >= ngroups) return;
    int lane = threadIdx.x & 63;
    const float2 v2 = *reinterpret_cast<const float2*>(in + (size_t)gid * 128 + lane * 2);
    float v0 = v2.x, v1 = v2.y;
    { float t0 = v0 + v1, t1 = v0 - v1; v0 = t0; v1 = t1; }
#pragma unroll
    for (int m = 1; m <= 32; m <<= 1) {
        float b0 = __shfl_xor(v0, m);
        float b1 = __shfl_xor(v1, m);
        if (lane & m) { v0 = b0 - v0; v1 = b1 - v1; }
        else          { v0 = v0 + b0; v1 = v1 + b1; }
    }
    const float s = 0.08838834764831843f;
    unsigned int o = (unsigned int)f2bf(v0 * s) | ((unsigned int)f2bf(v1 * s) << 16);
    *reinterpret_cast<unsigned int*>(out + (size_t)gid * 128 + lane * 2) = o;
}

__global__ void had_bf16_inplace(unsigned short* __restrict__ buf, int ngroups) {
    int gid = blockIdx.x * (blockDim.x >> 6) + (threadIdx.x >> 6);
    if (gid >= ngroups) return;
    int lane = threadIdx.x & 63;
    unsigned int pv = *reinterpret_cast<const unsigned int*>(buf + (size_t)gid * 128 + lane * 2);
    float v0 = __uint_as_float((pv & 0xFFFFu) << 16);
    float v1 = __uint_as_float(pv & 0xFFFF0000u);
    { float t0 = v0 + v1, t1 = v0 - v1; v0 = t0; v1 = t1; }
#pragma unroll
    for (int m = 1; m <= 32; m <<= 1) {
        float b0 = __shfl_xor(v0, m);
        float b1 = __shfl_xor(v1, m);
        if (lane & m) { v0 = b0 - v0; v1 = b1 - v1; }
        else          { v0 = v0 + b0; v1 = v1 + b1; }
    }
    const float s = 0.08838834764831843f;
    unsigned int o = (unsigned int)f2bf(v0 * s) | ((unsigned int)f2bf(v1 * s) << 16);
    *reinterpret_cast<unsigned int*>(buf + (size_t)gid * 128 + lane * 2) = o;
}

__global__ __launch_bounds__(256, 2)
void gemm_gateup_fb(const unsigned short* __restrict__ Xr,
                    const int* __restrict__ Wg, const float* __restrict__ Sg,
                    const int* __restrict__ Wu, const float* __restrict__ Su,
                    unsigned short* __restrict__ H)
{
    __shared__ __align__(16) unsigned short lA [128 * 64];
    __shared__ __align__(16) unsigned short lBg[128 * 64];
    __shared__ __align__(16) unsigned short lBu[128 * 64];
    const int MT = T_DIM / 128;
    const int bid = blockIdx.x;
    const int m0 = (bid % MT) * 128;
    const int n0 = (bid / MT) * 128;
    const int tid  = threadIdx.x;
    const int lane = tid & 63;
    const int wid  = tid >> 6;
    const int wr = wid >> 1, wc = wid & 1;
    f32x4 accG[4][4], accU[4][4];
#pragma unroll
    for (int i = 0; i < 4; ++i)
#pragma unroll
        for (int j = 0; j < 4; ++j) { accG[i][j] = (f32x4)0.0f; accU[i][j] = (f32x4)0.0f; }
    const int arow = lane >> 3;
    const int acol = (lane & 7) * 8;
    const int SStride = D_DIM / GRP;
    for (int k0 = 0; k0 < D_DIM; k0 += 64) {
        __syncthreads();
#pragma unroll
        for (int it = 0; it < 4; ++it) {
            int chunk = wid * 4 + it;
            const unsigned short* gp = Xr + (size_t)(m0 + chunk * 8 + arow) * D_DIM + k0 + acol;
            __builtin_amdgcn_global_load_lds((gmem_void*)gp, (lds_void*)(lA + chunk * 512), 16, 0, 0);
        }
        const int g = k0 >> 7;
#pragma unroll
        for (int i = 0; i < 8; ++i) {
            int linear = i * 1024 + tid * 4;
            int r = linear >> 6;
            int c = linear & 63;
            const int32x4 wg = *reinterpret_cast<const int32x4*>(Wg + (size_t)(n0 + r) * D_DIM + k0 + c);
            const int32x4 wu = *reinterpret_cast<const int32x4*>(Wu + (size_t)(n0 + r) * D_DIM + k0 + c);
            float scg = Sg[(size_t)(n0 + r) * SStride + g];
            float scu = Su[(size_t)(n0 + r) * SStride + g];
            unsigned int g01 = (unsigned int)f2bf((float)(wg.x - 8) * scg) | ((unsigned int)f2bf((float)(wg.y - 8) * scg) << 16);
            unsigned int g23 = (unsigned int)f2bf((float)(wg.z - 8) * scg) | ((unsigned int)f2bf((float)(wg.w - 8) * scg) << 16);
            unsigned int u01 = (unsigned int)f2bf((float)(wu.x - 8) * scu) | ((unsigned int)f2bf((float)(wu.y - 8) * scu) << 16);
            unsigned int u23 = (unsigned int)f2bf((float)(wu.z - 8) * scu) | ((unsigned int)f2bf((float)(wu.w - 8) * scu) << 16);
            *reinterpret_cast<uint2*>(lBg + r * 64 + c) = make_uint2(g01, g23);
            *reinterpret_cast<uint2*>(lBu + r * 64 + c) = make_uint2(u01, u23);
        }
        __syncthreads();
#pragma unroll
        for (int ks = 0; ks < 2; ++ks) {
            const int koff = ks * 32 + (lane >> 4) * 8;
            bf16x8 af[4], bg[4], bu[4];
#pragma unroll
            for (int mi = 0; mi < 4; ++mi)
                af[mi] = *reinterpret_cast<const bf16x8*>(lA + (wr * 64 + mi * 16 + (lane & 15)) * 64 + koff);
#pragma unroll
            for (int ni = 0; ni < 4; ++ni) {
                bg[ni] = *reinterpret_cast<const bf16x8*>(lBg + (wc * 64 + ni * 16 + (lane & 15)) * 64 + koff);
                bu[ni] = *reinterpret_cast<const bf16x8*>(lBu + (wc * 64 + ni * 16 + (lane & 15)) * 64 + koff);
            }
#pragma unroll
            for (int mi = 0; mi < 4; ++mi)
#pragma unroll
                for (int ni = 0; ni < 4; ++ni) {
                    accG[mi][ni] = __builtin_amdgcn_mfma_f32_16x16x32_bf16(af[mi], bg[ni], accG[mi][ni], 0, 0, 0);
                    accU[mi][ni] = __builtin_amdgcn_mfma_f32_16x16x32_bf16(af[mi], bu[ni], accU[mi][ni], 0, 0, 0);
                }
        }
    }
#pragma unroll
    for (int mi = 0; mi < 4; ++mi)
#pragma unroll
        for (int ni = 0; ni < 4; ++ni) {
            const int col = n0 + wc * 64 + ni * 16 + (lane & 15);
#pragma unroll
            for (int r = 0; r < 4; ++r) {
                const int row = m0 + wr * 64 + mi * 16 + (lane >> 4) * 4 + r;
                float gv = accG[mi][ni][r];
                float uv = accU[mi][ni][r];
                float hv = (gv / (1.0f + __expf(-gv))) * uv;
                H[(size_t)row * I_DIM + col] = f2bf(hv);
            }
        }
}

__global__ __launch_bounds__(256, 2)
void gemm_down_fb(const unsigned short* __restrict__ Hr,
                  const int* __restrict__ Wd, const float* __restrict__ Sd,
                  float* __restrict__ Out)
{
    __shared__ __align__(16) unsigned short lA[128 * 64];
    __shared__ __align__(16) unsigned short lB[128 * 64];
    const int MT = T_DIM / 128;
    const int bid = blockIdx.x;
    const int m0 = (bid % MT) * 128;
    const int n0 = (bid / MT) * 128;
    const int tid  = threadIdx.x;
    const int lane = tid & 63;
    const int wid  = tid >> 6;
    const int wr = wid >> 1, wc = wid & 1;
    f32x4 acc[4][4];
#pragma unroll
    for (int i = 0; i < 4; ++i)
#pragma unroll
        for (int j = 0; j < 4; ++j) acc[i][j] = (f32x4)0.0f;
    const int arow = lane >> 3;
    const int acol = (lane & 7) * 8;
    const int SStride = I_DIM / GRP;
    for (int k0 = 0; k0 < I_DIM; k0 += 64) {
        __syncthreads();
#pragma unroll
        for (int it = 0; it < 4; ++it) {
            int chunk = wid * 4 + it;
            const unsigned short* gp = Hr + (size_t)(m0 + chunk * 8 + arow) * I_DIM + k0 + acol;
            __builtin_amdgcn_global_load_lds((gmem_void*)gp, (lds_void*)(lA + chunk * 512), 16, 0, 0);
        }
        const int g = k0 >> 7;
#pragma unroll
        for (int i = 0; i < 8; ++i) {
            int linear = i * 1024 + tid * 4;
            int r = linear >> 6;
            int c = linear & 63;
            const int32x4 wd = *reinterpret_cast<const int32x4*>(Wd + (size_t)(n0 + r) * I_DIM + k0 + c);
            float sc = Sd[(size_t)(n0 + r) * SStride + g];
            unsigned int d01 = (unsigned int)f2bf((float)(wd.x - 8) * sc) | ((unsigned int)f2bf((float)(wd.y - 8) * sc) << 16);
            unsigned int d23 = (unsigned int)f2bf((float)(wd.z - 8) * sc) | ((unsigned int)f2bf((float)(wd.w - 8) * sc) << 16);
            *reinterpret_cast<uint2*>(lB + r * 64 + c) = make_uint2(d01, d23);
        }
        __syncthreads();
#pragma unroll
        for (int ks = 0; ks < 2; ++ks) {
            const int koff = ks * 32 + (lane >> 4) * 8;
            bf16x8 af[4], bfr[4];
#pragma unroll
            for (int mi = 0; mi < 4; ++mi)
                af[mi] = *reinterpret_cast<const bf16x8*>(lA + (wr * 64 + mi * 16 + (lane & 15)) * 64 + koff);
#pragma unroll
            for (int ni = 0; ni < 4; ++ni)
                bfr[ni] = *reinterpret_cast<const bf16x8*>(lB + (wc * 64 + ni * 16 + (lane & 15)) * 64 + koff);
#pragma unroll
            for (int mi = 0; mi < 4; ++mi)
#pragma unroll
                for (int ni = 0; ni < 4; ++ni)
                    acc[mi][ni] = __builtin_amdgcn_mfma_f32_16x16x32_bf16(af[mi], bfr[ni], acc[mi][ni], 0, 0, 0);
        }
    }
#pragma unroll
    for (int mi = 0; mi < 4; ++mi)
#pragma unroll
        for (int ni = 0; ni < 4; ++ni) {
            const int col = n0 + wc * 64 + ni * 16 + (lane & 15);
#pragma unroll
            for (int r = 0; r < 4; ++r) {
                const int row = m0 + wr * 64 + mi * 16 + (lane >> 4) * 4 + r;
                Out[(size_t)row * D_DIM + col] = acc[mi][ni][r];
            }
        }
}

extern "C" void kernel_launch(void* const* d_in, const int* in_sizes, int n_in,
                              void* d_out, int out_size, void* d_ws, size_t ws_size,
                              hipStream_t stream) {
    const float* x       = (const float*)d_in[0];
    const int*   wq_gate = (const int*)d_in[1];
    const float* s_gate  = (const float*)d_in[2];
    const int*   wq_up   = (const int*)d_in[3];
    const float* s_up    = (const float*)d_in[4];
    const int*   wq_down = (const int*)d_in[5];
    const float* s_down  = (const float*)d_in[6];
    float* out = (float*)d_out;

    const size_t XR_E = (size_t)T_DIM * D_DIM;      // 16.8M elems
    const size_t H_E  = (size_t)T_DIM * I_DIM;      // 50.3M
    const size_t W_E  = (size_t)I_DIM * D_DIM;      // 50.3M
    const size_t need = (XR_E + H_E + 2 * W_E) * 2; // 335.5 MB (same check as before)

    char* base = (char*)d_ws;

    if (ws_size >= need) {
        // layout: xq i8 | xs f32 | h bf16 | hq i8 | hs f32 | w8a | w8b   (~258 MB)
        signed char*    xq = (signed char*)base;
        float*          xs = (float*)(base + XR_E);
        unsigned short* h  = (unsigned short*)(base + XR_E + (XR_E / 128) * 4);
        signed char*    hq = (signed char*)((char*)h + H_E * 2);
        float*          hs = (float*)((char*)hq + H_E);
        signed char*    w8a = (signed char*)((char*)hs + (H_E / 128) * 4);
        signed char*    w8b = w8a + W_E;

        // 1) xq,xs = int8-quant(hadamard(x))
        {
            int ngroups = (int)(XR_E / 128);
            had_f32_to_i8<<<dim3(ngroups / 4), dim3(256), 0, stream>>>(x, xq, xs, ngroups);
        }
        // 2) repack gate & up weights -> int8 (exact)
        int total8 = (int)(W_E / 8);
        repack_w8<<<dim3((total8 + 255) / 256), dim3(256), 0, stream>>>(wq_gate, w8a, total8);
        repack_w8<<<dim3((total8 + 255) / 256), dim3(256), 0, stream>>>(wq_up,   w8b, total8);
        // 3) gate = xq @ w8a^T (scaled) -> h bf16
        gemm_i8<0><<<dim3((T_DIM / 256) * (I_DIM / 256)), dim3(512), 0, stream>>>(
            xq, xs, w8a, s_gate, (void*)h, T_DIM, I_DIM, D_DIM);
        // 4) h = silu(gate) * (xq @ w8b^T)
        gemm_i8<1><<<dim3((T_DIM / 256) * (I_DIM / 256)), dim3(512), 0, stream>>>(
            xq, xs, w8b, s_up, (void*)h, T_DIM, I_DIM, D_DIM);
        // 5) hq,hs = int8-quant(hadamard(h))
        {
            int ngroups = (int)(H_E / 128);
            had_bf16_to_i8<<<dim3(ngroups / 4), dim3(256), 0, stream>>>(h, hq, hs, ngroups);
        }
        // 6) repack down weights (reuse w8a)
        repack_w8<<<dim3((total8 + 255) / 256), dim3(256), 0, stream>>>(wq_down, w8a, total8);
        // 7) out = hq @ w8a^T (scaled), f32
        gemm_i8<2><<<dim3((T_DIM / 256) * (D_DIM / 256)), dim3(512), 0, stream>>>(
            hq, hs, w8a, s_down, (void*)out, T_DIM, D_DIM, I_DIM);
    } else {
        // fallback: round-1 verified bf16 path
        unsigned short* xr = (unsigned short*)d_ws;
        unsigned short* h  = xr + XR_E;
        {
            int ngroups = (int)(XR_E / 128);
            had_f32_to_bf16<<<dim3(ngroups / 4), dim3(256), 0, stream>>>(x, xr, ngroups);
        }
        gemm_gateup_fb<<<dim3((T_DIM / 128) * (I_DIM / 128)), dim3(256), 0, stream>>>(
            xr, wq_gate, s_gate, wq_up, s_up, h);
        {
            int ngroups = (int)(H_E / 128);
            had_bf16_inplace<<<dim3(ngroups / 4), dim3(256), 0, stream>>>(h, ngroups);
        }
        gemm_down_fb<<<dim3((T_DIM / 128) * (D_DIM / 128)), dim3(256), 0, stream>>>(
            h, wq_down, s_down, out);
    }
}

// Round 17
// 1832.739 us; speedup vs baseline: 3.8285x; 3.8272x over previous
//
#include <hip/hip_runtime.h>
#include <hip/hip_bf16.h>
#include <cstdint>

#define T_DIM 4096
#define D_DIM 4096
#define I_DIM 12288
#define GRP   128

typedef __attribute__((ext_vector_type(8))) short bf16x8;
typedef __attribute__((ext_vector_type(4))) float f32x4;
typedef __attribute__((ext_vector_type(4))) int   int32x4;

typedef __attribute__((address_space(3))) void lds_void;
typedef const __attribute__((address_space(1))) void gmem_void;

static __device__ __forceinline__ unsigned short f2bf(float f) {
    unsigned int u = __float_as_uint(f);
    u += 0x7FFFu + ((u >> 16) & 1u);
    return (unsigned short)(u >> 16);
}
static __device__ __forceinline__ float bf2f(unsigned short b) {
    return __uint_as_float(((unsigned int)b) << 16);
}

// ---------- Hadamard + int8 quant (per-128-group scale), one wave per group --------
__global__ void had_f32_to_i8(const float* __restrict__ in, signed char* __restrict__ outq,
                              float* __restrict__ outs, int ngroups) {
    int gid = blockIdx.x * (blockDim.x >> 6) + (threadIdx.x >> 6);
    if (gid >= ngroups) return;
    int lane = threadIdx.x & 63;
    const float2 v2 = *reinterpret_cast<const float2*>(in + (size_t)gid * 128 + lane * 2);
    float v0 = v2.x, v1 = v2.y;
    { float t0 = v0 + v1, t1 = v0 - v1; v0 = t0; v1 = t1; }
#pragma unroll
    for (int m = 1; m <= 32; m <<= 1) {
        float b0 = __shfl_xor(v0, m);
        float b1 = __shfl_xor(v1, m);
        if (lane & m) { v0 = b0 - v0; v1 = b1 - v1; }
        else          { v0 = v0 + b0; v1 = v1 + b1; }
    }
    const float s = 0.08838834764831843f;  // 1/sqrt(128)
    v0 *= s; v1 *= s;
    float am = fmaxf(fabsf(v0), fabsf(v1));
#pragma unroll
    for (int m = 1; m <= 32; m <<= 1) am = fmaxf(am, __shfl_xor(am, m));
    float inv = (am > 0.f) ? 127.0f / am : 0.f;
    int q0 = (int)rintf(v0 * inv);
    int q1 = (int)rintf(v1 * inv);
    unsigned short pk = (unsigned short)((q0 & 0xff) | ((q1 & 0xff) << 8));
    *reinterpret_cast<unsigned short*>(outq + (size_t)gid * 128 + lane * 2) = pk;
    if (lane == 0) outs[gid] = (am > 0.f) ? am / 127.0f : 1.0f;
}

__global__ void had_bf16_to_i8(const unsigned short* __restrict__ in, signed char* __restrict__ outq,
                               float* __restrict__ outs, int ngroups) {
    int gid = blockIdx.x * (blockDim.x >> 6) + (threadIdx.x >> 6);
    if (gid >= ngroups) return;
    int lane = threadIdx.x & 63;
    unsigned int pv = *reinterpret_cast<const unsigned int*>(in + (size_t)gid * 128 + lane * 2);
    float v0 = __uint_as_float((pv & 0xFFFFu) << 16);
    float v1 = __uint_as_float(pv & 0xFFFF0000u);
    { float t0 = v0 + v1, t1 = v0 - v1; v0 = t0; v1 = t1; }
#pragma unroll
    for (int m = 1; m <= 32; m <<= 1) {
        float b0 = __shfl_xor(v0, m);
        float b1 = __shfl_xor(v1, m);
        if (lane & m) { v0 = b0 - v0; v1 = b1 - v1; }
        else          { v0 = v0 + b0; v1 = v1 + b1; }
    }
    const float s = 0.08838834764831843f;
    v0 *= s; v1 *= s;
    float am = fmaxf(fabsf(v0), fabsf(v1));
#pragma unroll
    for (int m = 1; m <= 32; m <<= 1) am = fmaxf(am, __shfl_xor(am, m));
    float inv = (am > 0.f) ? 127.0f / am : 0.f;
    int q0 = (int)rintf(v0 * inv);
    int q1 = (int)rintf(v1 * inv);
    unsigned short pk = (unsigned short)((q0 & 0xff) | ((q1 & 0xff) << 8));
    *reinterpret_cast<unsigned short*>(outq + (size_t)gid * 128 + lane * 2) = pk;
    if (lane == 0) outs[gid] = (am > 0.f) ? am / 127.0f : 1.0f;
}

// ---------- weight repack: int4-in-int32 -> int8 (EXACT: value-8 in [-8,7]) --------
__global__ void repack_w8(const int* __restrict__ Wq, signed char* __restrict__ W8, int total8) {
    int t = blockIdx.x * blockDim.x + threadIdx.x;
    if (t >= total8) return;
    size_t base = (size_t)t * 8;
    const int32x4* p = reinterpret_cast<const int32x4*>(Wq + base);
    int32x4 a = p[0], b = p[1];
    unsigned int lo = ((unsigned int)(unsigned char)(a.x - 8)) |
                      ((unsigned int)(unsigned char)(a.y - 8) << 8) |
                      ((unsigned int)(unsigned char)(a.z - 8) << 16) |
                      ((unsigned int)(unsigned char)(a.w - 8) << 24);
    unsigned int hi = ((unsigned int)(unsigned char)(b.x - 8)) |
                      ((unsigned int)(unsigned char)(b.y - 8) << 8) |
                      ((unsigned int)(unsigned char)(b.z - 8) << 16) |
                      ((unsigned int)(unsigned char)(b.w - 8) << 24);
    *reinterpret_cast<uint2*>(W8 + base) = make_uint2(lo, hi);
}

// =====================================================================================
// int8 GEMM, 256(M) x 128(N) tile, BK=128 (= one quant group), r13-verified 2-barrier
// loop: stage(t+1)->buf^1 ; read frags(t) ; MFMA+flush ; vmcnt(0) ; barrier.
// 8 waves = 4m x 2n, per-wave 64x64 out -> facc[4][4] = 64 VGPR (the r15/r16 spill was
// facc=128). iq capped at 32 by flushing per n-half. Total demand ~190 < 256 budget.
// Numerics IDENTICAL to r15/r16 (absmax 0.4375 verified): exact int8 weights +
// per-128-group activation scales; int32 accumulate exact within group; f32 flush.
// LDS: 2 buf x (A[256][128] 32KB | B[128][128] 16KB) + sclA[2][256] + sclB[2][128].
// Swizzle: row=128B=8 chunks; LDS chunk s holds global chunk s^(r&7); read (ks*4+kc)^(r&7).
// MODE 0: bf16 out; 1: h=silu(C)*acc in place (bf16); 2: f32 out.
// =====================================================================================

#define GBAR()  __builtin_amdgcn_s_barrier()
#define VMW0()  asm volatile("s_waitcnt vmcnt(0)" ::: "memory")

// stage A (256 rows x 128B = 32KB): 4 gload_lds/thread
#define STGA8(bb, kb)                                                                  \
  { _Pragma("unroll")                                                                  \
    for (int l_ = 0; l_ < 4; ++l_) {                                                   \
      const int idx_ = l_ * 512 + tid;                                                 \
      const int r_ = idx_ >> 3;                                                        \
      const int cg_ = (idx_ & 7) ^ (r_ & 7);                                           \
      const signed char* gp_ = A + (size_t)(m0 + r_) * K + (kb) + cg_ * 16;            \
      signed char* lp_ = lds8 + (bb) * 49152 + ((l_ * 8 + wid) << 10);                 \
      __builtin_amdgcn_global_load_lds((gmem_void*)gp_, (lds_void*)lp_, 16, 0, 0);     \
    } }

// stage B (128 rows x 128B = 16KB): 2 gload_lds/thread
#define STGB8(bb, kb)                                                                  \
  { _Pragma("unroll")                                                                  \
    for (int l_ = 0; l_ < 2; ++l_) {                                                   \
      const int idx_ = l_ * 512 + tid;                                                 \
      const int r_ = idx_ >> 3;                                                        \
      const int cg_ = (idx_ & 7) ^ (r_ & 7);                                           \
      const signed char* gp_ = W + (size_t)(n0 + r_) * K + (kb) + cg_ * 16;            \
      signed char* lp_ = lds8 + (bb) * 49152 + 32768 + ((l_ * 8 + wid) << 10);         \
      __builtin_amdgcn_global_load_lds((gmem_void*)gp_, (lds_void*)lp_, 16, 0, 0);     \
    } }

// stage scales for group g (waves duplicate writes of identical data: benign)
#define STGS8(bb, g)                                                                   \
  { const float* ap_ = AS + (size_t)(m0 + ((wid & 3) << 6) + lane) * Ksc + (g);        \
    __builtin_amdgcn_global_load_lds((gmem_void*)ap_,                                  \
        (lds_void*)&sclA[bb][(wid & 3) << 6], 4, 0, 0);                                \
    const float* wp_ = WS + (size_t)(n0 + ((wid & 1) << 6) + lane) * Ksc + (g);        \
    __builtin_amdgcn_global_load_lds((gmem_void*)wp_,                                  \
        (lds_void*)&sclB[bb][(wid & 1) << 6], 4, 0, 0); }

// read A frags (4 m x 2 ksub) + per-m-frag scale vectors
#define LDAF(bb)                                                                       \
  _Pragma("unroll")                                                                    \
  for (int mi_ = 0; mi_ < 4; ++mi_) {                                                  \
    int r_ = wr * 64 + mi_ * 16 + (lane & 15);                                         \
    _Pragma("unroll")                                                                  \
    for (int ks_ = 0; ks_ < 2; ++ks_)                                                  \
      af[mi_][ks_] = *reinterpret_cast<const int32x4*>(lds8 + (bb) * 49152             \
          + r_ * 128 + (((ks_ * 4 + kc) ^ (r_ & 7)) << 4));                            \
    asv[mi_] = *reinterpret_cast<const f32x4*>(                                        \
        &sclA[bb][wr * 64 + mi_ * 16 + ((lane >> 4) << 2)]);                           \
  }

// read B frags (4 n x 2 ksub) + per-n scale scalars
#define LDBF(bb)                                                                       \
  _Pragma("unroll")                                                                    \
  for (int ni_ = 0; ni_ < 4; ++ni_) {                                                  \
    int r_ = wc * 64 + ni_ * 16 + (lane & 15);                                         \
    _Pragma("unroll")                                                                  \
    for (int ks_ = 0; ks_ < 2; ++ks_)                                                  \
      bk[ni_][ks_] = *reinterpret_cast<const int32x4*>(lds8 + (bb) * 49152 + 32768     \
          + r_ * 128 + (((ks_ * 4 + kc) ^ (r_ & 7)) << 4));                            \
    wsv[ni_] = sclB[bb][wc * 64 + ni_ * 16 + (lane & 15)];                             \
  }

// compute + flush one n-half (2 n-frags): iq live = 4x2 = 32 regs max
#define NHALF(nh)                                                                      \
  { int32x4 iq[4][2];                                                                  \
    _Pragma("unroll")                                                                  \
    for (int mi_ = 0; mi_ < 4; ++mi_)                                                  \
    _Pragma("unroll")                                                                  \
    for (int nj_ = 0; nj_ < 2; ++nj_)                                                  \
      iq[mi_][nj_] = __builtin_amdgcn_mfma_i32_16x16x64_i8(                            \
          af[mi_][1], bk[(nh) * 2 + nj_][1],                                           \
          __builtin_amdgcn_mfma_i32_16x16x64_i8(af[mi_][0], bk[(nh) * 2 + nj_][0],     \
              (int32x4)0, 0, 0, 0), 0, 0, 0);                                          \
    _Pragma("unroll")                                                                  \
    for (int mi_ = 0; mi_ < 4; ++mi_)                                                  \
    _Pragma("unroll")                                                                  \
    for (int nj_ = 0; nj_ < 2; ++nj_)                                                  \
    _Pragma("unroll")                                                                  \
    for (int r_ = 0; r_ < 4; ++r_)                                                     \
      facc[mi_][(nh) * 2 + nj_][r_] += asv[mi_][r_] * wsv[(nh) * 2 + nj_]              \
          * (float)iq[mi_][nj_][r_]; }

template<int MODE>
__global__ __launch_bounds__(512, 2)
void gemm_i8(const signed char* __restrict__ A, const float* __restrict__ AS,
             const signed char* __restrict__ W, const float* __restrict__ WS,
             void* __restrict__ C, int M, int N, int K)
{
    __shared__ __align__(16) signed char lds8[98304];    // 2 buf x (A 32KB | B 16KB)
    __shared__ __align__(16) float sclA[2][256];
    __shared__ __align__(16) float sclB[2][128];

    const int Ksc = K >> 7;                       // groups per row
    const int MT = M >> 8;                        // 256-row tiles along M
    const int nwg = gridDim.x;
    const int bid = blockIdx.x;
    const int cpx = nwg >> 3;
    const int wg  = (bid & 7) * cpx + (bid >> 3); // bijective XCD swizzle
    const int m0 = (wg % MT) << 8;
    const int n0 = (wg / MT) << 7;

    const int tid  = threadIdx.x;
    const int lane = tid & 63;
    const int wid  = tid >> 6;                    // 0..7
    const int wr = wid >> 1;                      // 0..3 (M quarter)
    const int wc = wid & 1;                       // 0..1 (N half)
    const int kc = lane >> 4;                     // 16B k-chunk (0..3)

    f32x4 facc[4][4];
#pragma unroll
    for (int i = 0; i < 4; ++i)
#pragma unroll
        for (int j = 0; j < 4; ++j) facc[i][j] = (f32x4)0.0f;

    const int NT = K >> 7;                        // K-tiles of 128

    int32x4 af[4][2], bk[4][2];
    f32x4 asv[4];
    float wsv[4];

    // ---- prologue: stage tile 0 into buf 0 ----
    STGA8(0, 0); STGB8(0, 0); STGS8(0, 0);
    VMW0();
    GBAR();

    for (int t = 0; t < NT; ++t) {
        const int bb = t & 1;
        if (t + 1 < NT) {
            const int kn = (t + 1) << 7;
            STGA8(bb ^ 1, kn); STGB8(bb ^ 1, kn); STGS8(bb ^ 1, t + 1);
        }
        LDAF(bb); LDBF(bb);
        NHALF(0); NHALF(1);
        VMW0();                                   // next tile's DMA landed
        GBAR();                                   // all waves done reading bb
    }

    // ---- epilogue: D-frag col=lane&15, row=(lane>>4)*4+r ----
#pragma unroll
    for (int mi = 0; mi < 4; ++mi)
#pragma unroll
        for (int ni = 0; ni < 4; ++ni) {
            const int col = n0 + wc * 64 + ni * 16 + (lane & 15);
#pragma unroll
            for (int r = 0; r < 4; ++r) {
                const int row = m0 + wr * 64 + mi * 16 + ((lane >> 4) << 2) + r;
                const size_t idx = (size_t)row * N + col;
                if (MODE == 2) {
                    ((float*)C)[idx] = facc[mi][ni][r];
                } else if (MODE == 0) {
                    ((unsigned short*)C)[idx] = f2bf(facc[mi][ni][r]);
                } else {
                    float g = bf2f(((unsigned short*)C)[idx]);
                    float u = facc[mi][ni][r];
                    float h = (g / (1.0f + __expf(-g))) * u;
                    ((unsigned short*)C)[idx] = f2bf(h);
                }
            }
        }
}

// ============== FALLBACK (round-1 verified): bf16 had + in-loop dequant =============
__global__ void had_f32_to_bf16(const float* __restrict__ in, unsigned short* __restrict__ out,
                                int ngroups) {
    int gid = blockIdx.x * (blockDim.x >> 6) + (threadIdx.x >> 6);
    if (gid >= ngroups) return;
    int lane = threadIdx.x & 63;
    const float2 v2 = *reinterpret_cast<const float2*>(in + (size_t)gid * 128 + lane * 2);
    float v0 = v2.x, v1 = v2.y;
    { float t0 = v0 + v1, t1 = v0 - v1; v0 = t0; v1 = t1; }
#pragma unroll
    for (int m = 1; m <= 32; m <<= 1) {
        float b0 = __shfl_xor(v0, m);
        float b1 = __shfl_xor(v1, m);
        if (lane & m) { v0 = b0 - v0; v1 = b1 - v1; }
        else          { v0 = v0 + b0; v1 = v1 + b1; }
    }
    const float s = 0.08838834764831843f;
    unsigned int o = (unsigned int)f2bf(v0 * s) | ((unsigned int)f2bf(v1 * s) << 16);
    *reinterpret_cast<unsigned int*>(out + (size_t)gid * 128 + lane * 2) = o;
}

__global__ void had_bf16_inplace(unsigned short* __restrict__ buf, int ngroups) {
    int gid = blockIdx.x * (blockDim.x >> 6) + (threadIdx.x >> 6);
    if (gid >= ngroups) return;
    int lane = threadIdx.x & 63;
    unsigned int pv = *reinterpret_cast<const unsigned int*>(buf + (size_t)gid * 128 + lane * 2);
    float v0 = __uint_as_float((pv & 0xFFFFu) << 16);
    float v1 = __uint_as_float(pv & 0xFFFF0000u);
    { float t0 = v0 + v1, t1 = v0 - v1; v0 = t0; v1 = t1; }
#pragma unroll
    for (int m = 1; m <= 32; m <<= 1) {
        float b0 = __shfl_xor(v0, m);
        float b1 = __shfl_xor(v1, m);
        if (lane & m) { v0 = b0 - v0; v1 = b1 - v1; }
        else          { v0 = v0 + b0; v1 = v1 + b1; }
    }
    const float s = 0.08838834764831843f;
    unsigned int o = (unsigned int)f2bf(v0 * s) | ((unsigned int)f2bf(v1 * s) << 16);
    *reinterpret_cast<unsigned int*>(buf + (size_t)gid * 128 + lane * 2) = o;
}

__global__ __launch_bounds__(256, 2)
void gemm_gateup_fb(const unsigned short* __restrict__ Xr,
                    const int* __restrict__ Wg, const float* __restrict__ Sg,
                    const int* __restrict__ Wu, const float* __restrict__ Su,
                    unsigned short* __restrict__ H)
{
    __shared__ __align__(16) unsigned short lA [128 * 64];
    __shared__ __align__(16) unsigned short lBg[128 * 64];
    __shared__ __align__(16) unsigned short lBu[128 * 64];
    const int MT = T_DIM / 128;
    const int bid = blockIdx.x;
    const int m0 = (bid % MT) * 128;
    const int n0 = (bid / MT) * 128;
    const int tid  = threadIdx.x;
    const int lane = tid & 63;
    const int wid  = tid >> 6;
    const int wr = wid >> 1, wc = wid & 1;
    f32x4 accG[4][4], accU[4][4];
#pragma unroll
    for (int i = 0; i < 4; ++i)
#pragma unroll
        for (int j = 0; j < 4; ++j) { accG[i][j] = (f32x4)0.0f; accU[i][j] = (f32x4)0.0f; }
    const int arow = lane >> 3;
    const int acol = (lane & 7) * 8;
    const int SStride = D_DIM / GRP;
    for (int k0 = 0; k0 < D_DIM; k0 += 64) {
        __syncthreads();
#pragma unroll
        for (int it = 0; it < 4; ++it) {
            int chunk = wid * 4 + it;
            const unsigned short* gp = Xr + (size_t)(m0 + chunk * 8 + arow) * D_DIM + k0 + acol;
            __builtin_amdgcn_global_load_lds((gmem_void*)gp, (lds_void*)(lA + chunk * 512), 16, 0, 0);
        }
        const int g = k0 >> 7;
#pragma unroll
        for (int i = 0; i < 8; ++i) {
            int linear = i * 1024 + tid * 4;
            int r = linear >> 6;
            int c = linear & 63;
            const int32x4 wg = *reinterpret_cast<const int32x4*>(Wg + (size_t)(n0 + r) * D_DIM + k0 + c);
            const int32x4 wu = *reinterpret_cast<const int32x4*>(Wu + (size_t)(n0 + r) * D_DIM + k0 + c);
            float scg = Sg[(size_t)(n0 + r) * SStride + g];
            float scu = Su[(size_t)(n0 + r) * SStride + g];
            unsigned int g01 = (unsigned int)f2bf((float)(wg.x - 8) * scg) | ((unsigned int)f2bf((float)(wg.y - 8) * scg) << 16);
            unsigned int g23 = (unsigned int)f2bf((float)(wg.z - 8) * scg) | ((unsigned int)f2bf((float)(wg.w - 8) * scg) << 16);
            unsigned int u01 = (unsigned int)f2bf((float)(wu.x - 8) * scu) | ((unsigned int)f2bf((float)(wu.y - 8) * scu) << 16);
            unsigned int u23 = (unsigned int)f2bf((float)(wu.z - 8) * scu) | ((unsigned int)f2bf((float)(wu.w - 8) * scu) << 16);
            *reinterpret_cast<uint2*>(lBg + r * 64 + c) = make_uint2(g01, g23);
            *reinterpret_cast<uint2*>(lBu + r * 64 + c) = make_uint2(u01, u23);
        }
        __syncthreads();
#pragma unroll
        for (int ks = 0; ks < 2; ++ks) {
            const int koff = ks * 32 + (lane >> 4) * 8;
            bf16x8 af[4], bg[4], bu[4];
#pragma unroll
            for (int mi = 0; mi < 4; ++mi)
                af[mi] = *reinterpret_cast<const bf16x8*>(lA + (wr * 64 + mi * 16 + (lane & 15)) * 64 + koff);
#pragma unroll
            for (int ni = 0; ni < 4; ++ni) {
                bg[ni] = *reinterpret_cast<const bf16x8*>(lBg + (wc * 64 + ni * 16 + (lane & 15)) * 64 + koff);
                bu[ni] = *reinterpret_cast<const bf16x8*>(lBu + (wc * 64 + ni * 16 + (lane & 15)) * 64 + koff);
            }
#pragma unroll
            for (int mi = 0; mi < 4; ++mi)
#pragma unroll
                for (int ni = 0; ni < 4; ++ni) {
                    accG[mi][ni] = __builtin_amdgcn_mfma_f32_16x16x32_bf16(af[mi], bg[ni], accG[mi][ni], 0, 0, 0);
                    accU[mi][ni] = __builtin_amdgcn_mfma_f32_16x16x32_bf16(af[mi], bu[ni], accU[mi][ni], 0, 0, 0);
                }
        }
    }
#pragma unroll
    for (int mi = 0; mi < 4; ++mi)
#pragma unroll
        for (int ni = 0; ni < 4; ++ni) {
            const int col = n0 + wc * 64 + ni * 16 + (lane & 15);
#pragma unroll
            for (int r = 0; r < 4; ++r) {
                const int row = m0 + wr * 64 + mi * 16 + (lane >> 4) * 4 + r;
                float gv = accG[mi][ni][r];
                float uv = accU[mi][ni][r];
                float hv = (gv / (1.0f + __expf(-gv))) * uv;
                H[(size_t)row * I_DIM + col] = f2bf(hv);
            }
        }
}

__global__ __launch_bounds__(256, 2)
void gemm_down_fb(const unsigned short* __restrict__ Hr,
                  const int* __restrict__ Wd, const float* __restrict__ Sd,
                  float* __restrict__ Out)
{
    __shared__ __align__(16) unsigned short lA[128 * 64];
    __shared__ __align__(16) unsigned short lB[128 * 64];
    const int MT = T_DIM / 128;
    const int bid = blockIdx.x;
    const int m0 = (bid % MT) * 128;
    const int n0 = (bid / MT) * 128;
    const int tid  = threadIdx.x;
    const int lane = tid & 63;
    const int wid  = tid >> 6;
    const int wr = wid >> 1, wc = wid & 1;
    f32x4 acc[4][4];
#pragma unroll
    for (int i = 0; i < 4; ++i)
#pragma unroll
        for (int j = 0; j < 4; ++j) acc[i][j] = (f32x4)0.0f;
    const int arow = lane >> 3;
    const int acol = (lane & 7) * 8;
    const int SStride = I_DIM / GRP;
    for (int k0 = 0; k0 < I_DIM; k0 += 64) {
        __syncthreads();
#pragma unroll
        for (int it = 0; it < 4; ++it) {
            int chunk = wid * 4 + it;
            const unsigned short* gp = Hr + (size_t)(m0 + chunk * 8 + arow) * I_DIM + k0 + acol;
            __builtin_amdgcn_global_load_lds((gmem_void*)gp, (lds_void*)(lA + chunk * 512), 16, 0, 0);
        }
        const int g = k0 >> 7;
#pragma unroll
        for (int i = 0; i < 8; ++i) {
            int linear = i * 1024 + tid * 4;
            int r = linear >> 6;
            int c = linear & 63;
            const int32x4 wd = *reinterpret_cast<const int32x4*>(Wd + (size_t)(n0 + r) * I_DIM + k0 + c);
            float sc = Sd[(size_t)(n0 + r) * SStride + g];
            unsigned int d01 = (unsigned int)f2bf((float)(wd.x - 8) * sc) | ((unsigned int)f2bf((float)(wd.y - 8) * sc) << 16);
            unsigned int d23 = (unsigned int)f2bf((float)(wd.z - 8) * sc) | ((unsigned int)f2bf((float)(wd.w - 8) * sc) << 16);
            *reinterpret_cast<uint2*>(lB + r * 64 + c) = make_uint2(d01, d23);
        }
        __syncthreads();
#pragma unroll
        for (int ks = 0; ks < 2; ++ks) {
            const int koff = ks * 32 + (lane >> 4) * 8;
            bf16x8 af[4], bfr[4];
#pragma unroll
            for (int mi = 0; mi < 4; ++mi)
                af[mi] = *reinterpret_cast<const bf16x8*>(lA + (wr * 64 + mi * 16 + (lane & 15)) * 64 + koff);
#pragma unroll
            for (int ni = 0; ni < 4; ++ni)
                bfr[ni] = *reinterpret_cast<const bf16x8*>(lB + (wc * 64 + ni * 16 + (lane & 15)) * 64 + koff);
#pragma unroll
            for (int mi = 0; mi < 4; ++mi)
#pragma unroll
                for (int ni = 0; ni < 4; ++ni)
                    acc[mi][ni] = __builtin_amdgcn_mfma_f32_16x16x32_bf16(af[mi], bfr[ni], acc[mi][ni], 0, 0, 0);
        }
    }
#pragma unroll
    for (int mi = 0; mi < 4; ++mi)
#pragma unroll
        for (int ni = 0; ni < 4; ++ni) {
            const int col = n0 + wc * 64 + ni * 16 + (lane & 15);
#pragma unroll
            for (int r = 0; r < 4; ++r) {
                const int row = m0 + wr * 64 + mi * 16 + (lane >> 4) * 4 + r;
                Out[(size_t)row * D_DIM + col] = acc[mi][ni][r];
            }
        }
}

extern "C" void kernel_launch(void* const* d_in, const int* in_sizes, int n_in,
                              void* d_out, int out_size, void* d_ws, size_t ws_size,
                              hipStream_t stream) {
    const float* x       = (const float*)d_in[0];
    const int*   wq_gate = (const int*)d_in[1];
    const float* s_gate  = (const float*)d_in[2];
    const int*   wq_up   = (const int*)d_in[3];
    const float* s_up    = (const float*)d_in[4];
    const int*   wq_down = (const int*)d_in[5];
    const float* s_down  = (const float*)d_in[6];
    float* out = (float*)d_out;

    const size_t XR_E = (size_t)T_DIM * D_DIM;      // 16.8M elems
    const size_t H_E  = (size_t)T_DIM * I_DIM;      // 50.3M
    const size_t W_E  = (size_t)I_DIM * D_DIM;      // 50.3M
    const size_t need = (XR_E + H_E + 2 * W_E) * 2; // 335.5 MB

    char* base = (char*)d_ws;

    if (ws_size >= need) {
        // layout: xq i8 | xs f32 | h bf16 | hq i8 | hs f32 | w8a | w8b   (~258 MB)
        signed char*    xq = (signed char*)base;
        float*          xs = (float*)(base + XR_E);
        unsigned short* h  = (unsigned short*)(base + XR_E + (XR_E / 128) * 4);
        signed char*    hq = (signed char*)((char*)h + H_E * 2);
        float*          hs = (float*)((char*)hq + H_E);
        signed char*    w8a = (signed char*)((char*)hs + (H_E / 128) * 4);
        signed char*    w8b = w8a + W_E;

        // 1) xq,xs = int8-quant(hadamard(x))
        {
            int ngroups = (int)(XR_E / 128);
            had_f32_to_i8<<<dim3(ngroups / 4), dim3(256), 0, stream>>>(x, xq, xs, ngroups);
        }
        // 2) repack gate & up weights -> int8 (exact)
        int total8 = (int)(W_E / 8);
        repack_w8<<<dim3((total8 + 255) / 256), dim3(256), 0, stream>>>(wq_gate, w8a, total8);
        repack_w8<<<dim3((total8 + 255) / 256), dim3(256), 0, stream>>>(wq_up,   w8b, total8);
        // 3) gate = xq @ w8a^T (scaled) -> h bf16
        gemm_i8<0><<<dim3((T_DIM / 256) * (I_DIM / 128)), dim3(512), 0, stream>>>(
            xq, xs, w8a, s_gate, (void*)h, T_DIM, I_DIM, D_DIM);
        // 4) h = silu(gate) * (xq @ w8b^T)
        gemm_i8<1><<<dim3((T_DIM / 256) * (I_DIM / 128)), dim3(512), 0, stream>>>(
            xq, xs, w8b, s_up, (void*)h, T_DIM, I_DIM, D_DIM);
        // 5) hq,hs = int8-quant(hadamard(h))
        {
            int ngroups = (int)(H_E / 128);
            had_bf16_to_i8<<<dim3(ngroups / 4), dim3(256), 0, stream>>>(h, hq, hs, ngroups);
        }
        // 6) repack down weights (reuse w8a)
        repack_w8<<<dim3((total8 + 255) / 256), dim3(256), 0, stream>>>(wq_down, w8a, total8);
        // 7) out = hq @ w8a^T (scaled), f32
        gemm_i8<2><<<dim3((T_DIM / 256) * (D_DIM / 128)), dim3(512), 0, stream>>>(
            hq, hs, w8a, s_down, (void*)out, T_DIM, D_DIM, I_DIM);
    } else {
        // fallback: round-1 verified bf16 path
        unsigned short* xr = (unsigned short*)d_ws;
        unsigned short* h  = xr + XR_E;
        {
            int ngroups = (int)(XR_E / 128);
            had_f32_to_bf16<<<dim3(ngroups / 4), dim3(256), 0, stream>>>(x, xr, ngroups);
        }
        gemm_gateup_fb<<<dim3((T_DIM / 128) * (I_DIM / 128)), dim3(256), 0, stream>>>(
            xr, wq_gate, s_gate, wq_up, s_up, h);
        {
            int ngroups = (int)(H_E / 128);
            had_bf16_inplace<<<dim3(ngroups / 4), dim3(256), 0, stream>>>(h, ngroups);
        }
        gemm_down_fb<<<dim3((T_DIM / 128) * (D_DIM / 128)), dim3(256), 0, stream>>>(
            h, wq_down, s_down, out);
    }
}